// Round 6
// baseline (324.188 us; speedup 1.0000x reference)
//
#include <hip/hip_runtime.h>
#include <cstddef>

constexpr int B_  = 16;
constexpr int K_  = 5;
constexpr int C_  = 256;
constexpr int HW_ = 128 * 128;
constexpr int Q_  = 64;
constexpr float T_ = 0.2f;
constexpr int WPS_   = HW_ / 4;        // packed words per sample = 4096
constexpr int WTOT_  = B_ * WPS_;      // 65536 words total
constexpr int CPS_   = WPS_ / 256;     // 16 chunks (of 256 words) per sample

typedef float f4 __attribute__((ext_vector_type(4)));

// ---------------------------------------------------------------------------
// Kernel 1: prediction (byte-packed, 4 px/word) + per-chunk counts, balanced.
// 128 blocks; each thread handles word idx (first half: samples 0..7) and
// word idx+32768 (samples 8..15) -> labeled/unlabeled work evenly mixed.
// Chunk g (256 words) count vector -> counts_blk[g*K..]; chunk = word >> 8.
// Block 0 zeroes the 16 per-sample flags + 1 global flag for segsum's fused
// loss tail (ordered by the kernel-boundary dependency).
// ---------------------------------------------------------------------------
__global__ __launch_bounds__(256) void pred_kernel(
    const float* __restrict__ res1, const int* __restrict__ gt,
    const int* __restrict__ label_bs, unsigned int* __restrict__ predp,
    int* __restrict__ counts_blk, int* __restrict__ flags)
{
    if (blockIdx.x == 0 && threadIdx.x < B_ + 1) flags[threadIdx.x] = 0;

    int lb = label_bs[0];
    int tid = threadIdx.x, lane = tid & 63, wv = tid >> 6;
    __shared__ int redc[4][K_];

    #pragma unroll
    for (int h = 0; h < 2; ++h) {
        int idx = h * (WTOT_ / 2) + blockIdx.x * 256 + tid;
        int b  = idx >> 12;
        int p4 = idx & 4095;
        int k0, k1, k2, k3;
        if (b < lb) {
            int4 g = reinterpret_cast<const int4*>(gt + (size_t)b * HW_)[p4];
            k0 = g.x; k1 = g.y; k2 = g.z; k3 = g.w;
        } else {
            const f4* r = reinterpret_cast<const f4*>(res1 + (size_t)b * K_ * HW_) + p4;
            f4 best = __builtin_nontemporal_load(r);
            k0 = k1 = k2 = k3 = 0;
            #pragma unroll
            for (int k = 1; k < K_; ++k) {
                f4 v = __builtin_nontemporal_load(r + (size_t)k * WPS_);
                if (v.x > best.x) { best.x = v.x; k0 = k; }   // strict >: first max
                if (v.y > best.y) { best.y = v.y; k1 = k; }
                if (v.z > best.z) { best.z = v.z; k2 = k; }
                if (v.w > best.w) { best.w = v.w; k3 = k; }
            }
        }
        predp[idx] = (unsigned)(k0 & 0xFF) | ((unsigned)(k1 & 0xFF) << 8)
                   | ((unsigned)(k2 & 0xFF) << 16) | ((unsigned)(k3 & 0xFF) << 24);

        #pragma unroll
        for (int k = 0; k < K_; ++k) {
            int v = (k0 == k) + (k1 == k) + (k2 == k) + (k3 == k);
            #pragma unroll
            for (int off = 32; off > 0; off >>= 1) v += __shfl_down(v, off);
            if (lane == 0) redc[wv][k] = v;
        }
        __syncthreads();
        int chunk = h * 128 + blockIdx.x;     // == idx >> 8 (block-uniform)
        if (tid < K_)
            counts_blk[chunk * K_ + tid] =
                redc[0][tid] + redc[1][tid] + redc[2][tid] + redc[3][tid];
        __syncthreads();                       // redc reused next half
    }
}

// ---------------------------------------------------------------------------
// Kernel 2: masked segment sums (NT float4 streaming, one block per (b,c)
// row, unique-owner writes) + FUSED contrastive tail: the last-finishing
// block of each sample computes that sample's whole loss; the globally last
// block reduces per_sample -> out. Deterministic: the tail reads the same
// global data in a fixed order regardless of which block executes it.
// ---------------------------------------------------------------------------
__global__ __launch_bounds__(256) void segsum_kernel(
    const float* __restrict__ fea, const unsigned int* __restrict__ predp,
    const int* __restrict__ counts_blk, const float* __restrict__ queues,
    float* __restrict__ sums, int* __restrict__ flags,
    float* __restrict__ per_sample, float* __restrict__ out)
{
    int bc = blockIdx.x;
    int b = bc >> 8;              // / C_
    int c = bc & (C_ - 1);
    int tid = threadIdx.x, lane = tid & 63, wv = tid >> 6;
    const f4* frow = reinterpret_cast<const f4*>(fea + ((size_t)b * C_ + c) * HW_);
    const unsigned int* prow = predp + (size_t)b * WPS_;

    float acc[K_] = {};
    #pragma unroll 4
    for (int i = tid; i < WPS_; i += 256) {
        f4 v = __builtin_nontemporal_load(frow + i);
        unsigned u = prow[i];
        int k0 = u & 255, k1 = (u >> 8) & 255, k2 = (u >> 16) & 255, k3 = u >> 24;
        #pragma unroll
        for (int k = 0; k < K_; ++k) {
            acc[k] += (k0 == k ? v.x : 0.f)
                    + (k1 == k ? v.y : 0.f)
                    + (k2 == k ? v.z : 0.f)
                    + (k3 == k ? v.w : 0.f);
        }
    }

    __shared__ float red[4][K_];
    #pragma unroll
    for (int k = 0; k < K_; ++k) {
        float v = acc[k];
        #pragma unroll
        for (int off = 32; off > 0; off >>= 1) v += __shfl_down(v, off);
        if (lane == 0) red[wv][k] = v;
    }
    __syncthreads();
    if (tid < K_)
        sums[((size_t)b * K_ + tid) * C_ + c] =
            red[0][tid] + red[1][tid] + red[2][tid] + red[3][tid];

    // ---- per-sample last-block loss tail ----
    __shared__ int lastS;
    if (tid == 0) {
        __threadfence();
        lastS = (atomicAdd(&flags[b], 1) == C_ - 1);
    }
    __syncthreads();
    if (lastS) {
        __threadfence();   // acquire: all sample-b sums visible

        __shared__ int   cnt_s[K_];
        __shared__ float key[K_][C_];
        __shared__ float wred[4];
        __shared__ float sumE_s[K_][K_];
        __shared__ float lpos_s[K_][Q_];
        __shared__ float logprob_s[K_];
        __shared__ int   lastG;

        if (tid < K_) {
            int s = 0;
            #pragma unroll
            for (int i = 0; i < CPS_; ++i)
                s += counts_blk[(b * CPS_ + i) * K_ + tid];
            cnt_s[tid] = s;
        }
        __syncthreads();

        // normalized mean key per class (thread tid owns channel tid)
        for (int k = 0; k < K_; ++k) {
            float m = sums[((size_t)b * K_ + k) * C_ + tid] /
                      fmaxf((float)cnt_s[k], 1.0f);
            float s = m * m;
            #pragma unroll
            for (int off = 32; off > 0; off >>= 1) s += __shfl_down(s, off);
            if (lane == 0) wred[wv] = s;
            __syncthreads();
            float nrm = sqrtf(wred[0] + wred[1] + wred[2] + wred[3]);
            key[k][tid] = m / fmaxf(nrm, 1e-12f);
            __syncthreads();   // wred reused
        }

        // sim over 25 (k,j) pairs; lanes = q
        for (int pair = wv; pair < K_ * K_; pair += 4) {
            int k = pair / K_;
            int j = pair - k * K_;
            int prev = -1;
            #pragma unroll
            for (int jj = 0; jj < K_; ++jj)
                if (jj < k && cnt_s[jj] > 0) prev = jj;
            int pk = prev < 0 ? 0 : prev;           // query = keys[max(prev,0)]
            const float* qj = queues + (size_t)j * C_ * Q_ + lane;
            float a = 0.f;
            for (int cc = 0; cc < C_; ++cc)
                a += key[pk][cc] * qj[(size_t)cc * Q_];
            a = a / T_;
            float se = expf(a);
            #pragma unroll
            for (int off = 32; off > 0; off >>= 1) se += __shfl_down(se, off);
            if (lane == 0) sumE_s[k][j] = se;
            if (j == k) lpos_s[k][lane] = a;
        }
        __syncthreads();

        for (int k = wv; k < K_; k += 4) {
            float neg = 0.f;
            #pragma unroll
            for (int j = 0; j < K_; ++j)
                if (j != k) neg += sumE_s[k][j];
            float lp = lpos_s[k][lane];
            float term = lp - logf(expf(lp) + neg);
            #pragma unroll
            for (int off = 32; off > 0; off >>= 1) term += __shfl_down(term, off);
            if (lane == 0) logprob_s[k] = term * (1.0f / (float)Q_);
        }
        __syncthreads();

        if (tid == 0) {
            int last = -1, smallest = -1, npres = 0;
            float lsum = 0.f;
            #pragma unroll
            for (int kk = 0; kk < K_; ++kk) {
                bool pres = cnt_s[kk] > 0;
                bool valid = pres && smallest >= 0 && last >= 0;
                if (valid) lsum += -logprob_s[kk];
                if (pres && smallest < 0) smallest = kk;
                if (pres) { ++npres; last = kk; }
            }
            int denom = npres - 1;
            per_sample[b] = (denom > 0) ? (lsum / (float)denom) : 0.f;
        }
        __syncthreads();

        // ---- global last block: final reduction ----
        if (tid == 0) {
            __threadfence();
            lastG = (atomicAdd(&flags[B_], 1) == B_ - 1);
        }
        __syncthreads();
        if (lastG && wv == 0) {
            __threadfence();
            float per = (lane < B_) ? per_sample[lane] : 0.f;
            #pragma unroll
            for (int off = 32; off > 0; off >>= 1) per += __shfl_down(per, off);
            if (lane == 0) out[0] = per / (float)B_;
        }
    }
}

// ---------------------------------------------------------------------------
extern "C" void kernel_launch(void* const* d_in, const int* in_sizes, int n_in,
                              void* d_out, int out_size, void* d_ws, size_t ws_size,
                              hipStream_t stream)
{
    const float* res1     = (const float*)d_in[0];
    const float* fea1     = (const float*)d_in[1];
    const float* queues   = (const float*)d_in[2];
    const int*   gt       = (const int*)d_in[3];
    const int*   label_bs = (const int*)d_in[4];
    float* out = (float*)d_out;

    char* ws = (char*)d_ws;
    unsigned int* predp = (unsigned int*)ws;                        // 256 KB
    float* sums       = (float*)(ws + (size_t)WTOT_ * 4);           // B*K*C floats
    int*   counts_blk = (int*)(sums + (size_t)B_ * K_ * C_);        // 256*K ints
    int*   flags      = counts_blk + (WTOT_ / 256) * K_;            // B+1 ints
    float* per_sample = (float*)(flags + B_ + 1);                   // B floats

    pred_kernel<<<128, 256, 0, stream>>>(res1, gt, label_bs, predp,
                                         counts_blk, flags);
    segsum_kernel<<<B_ * C_, 256, 0, stream>>>(fea1, predp, counts_blk, queues,
                                               sums, flags, per_sample, out);
}

// Round 7
// 102.817 us; speedup vs baseline: 3.1530x; 3.1530x over previous
//
#include <hip/hip_runtime.h>
#include <cstddef>

constexpr int B_  = 16;
constexpr int K_  = 5;
constexpr int C_  = 256;
constexpr int HW_ = 128 * 128;
constexpr int Q_  = 64;
constexpr float T_ = 0.2f;
constexpr int WPS_ = HW_ / 4;   // packed words per sample = 4096
constexpr int PB_  = 16;        // pred blocks per sample (4096/256)

typedef float f4 __attribute__((ext_vector_type(4)));

// ---------------------------------------------------------------------------
// Kernel 1: per-pixel prediction (byte-packed, 4 px/uint) + per-block counts.
// pred[b,p] = gt[b,p] if b < label_bs else first-max argmax_k res1[b,k,p].
// Each block owns a disjoint 1024-pixel chunk -> direct count writes, no
// atomics, no memset. Block 0 also zeroes the loss completion flag (ordered
// before loss_kernel by graph edges).
// ---------------------------------------------------------------------------
__global__ __launch_bounds__(256) void pred_kernel(
    const float* __restrict__ res1, const int* __restrict__ gt,
    const int* __restrict__ label_bs, unsigned int* __restrict__ predp,
    int* __restrict__ counts_blk, int* __restrict__ flag)
{
    if (blockIdx.x == 0 && threadIdx.x == 0) *flag = 0;

    int idx = blockIdx.x * 256 + threadIdx.x;   // word index, 0 .. B*HW/4-1
    int b  = idx >> 12;                         // 4096 words per sample
    int p4 = idx & 4095;
    int lb = label_bs[0];
    int k0, k1, k2, k3;
    if (b < lb) {
        int4 g = reinterpret_cast<const int4*>(gt + (size_t)b * HW_)[p4];
        k0 = g.x; k1 = g.y; k2 = g.z; k3 = g.w;
    } else {
        const f4* r = reinterpret_cast<const f4*>(res1 + (size_t)b * K_ * HW_) + p4;
        f4 best = __builtin_nontemporal_load(r);
        k0 = k1 = k2 = k3 = 0;
        #pragma unroll
        for (int k = 1; k < K_; ++k) {
            f4 v = __builtin_nontemporal_load(r + (size_t)k * WPS_);
            if (v.x > best.x) { best.x = v.x; k0 = k; }   // strict >: first max
            if (v.y > best.y) { best.y = v.y; k1 = k; }
            if (v.z > best.z) { best.z = v.z; k2 = k; }
            if (v.w > best.w) { best.w = v.w; k3 = k; }
        }
    }
    predp[idx] = (unsigned)(k0 & 0xFF) | ((unsigned)(k1 & 0xFF) << 8)
               | ((unsigned)(k2 & 0xFF) << 16) | ((unsigned)(k3 & 0xFF) << 24);

    int cnt[K_];
    #pragma unroll
    for (int k = 0; k < K_; ++k)
        cnt[k] = (k0 == k) + (k1 == k) + (k2 == k) + (k3 == k);

    int lane = threadIdx.x & 63, wv = threadIdx.x >> 6;
    __shared__ int redc[4][K_];
    #pragma unroll
    for (int k = 0; k < K_; ++k) {
        int v = cnt[k];
        #pragma unroll
        for (int off = 32; off > 0; off >>= 1) v += __shfl_down(v, off);
        if (lane == 0) redc[wv][k] = v;
    }
    __syncthreads();
    if (threadIdx.x < K_)
        counts_blk[blockIdx.x * K_ + threadIdx.x] =
            redc[0][threadIdx.x] + redc[1][threadIdx.x] +
            redc[2][threadIdx.x] + redc[3][threadIdx.x];
}

// ---------------------------------------------------------------------------
// Kernel 2: masked segment sums. One block per (b,c) row (4096 blocks);
// NT float4 streaming + byte-packed preds; unique-owner direct writes,
// no atomics, perfectly uniform work. (Round-4 known-good config.)
// ---------------------------------------------------------------------------
__global__ __launch_bounds__(256) void segsum_kernel(
    const float* __restrict__ fea, const unsigned int* __restrict__ predp,
    float* __restrict__ sums)
{
    int bc = blockIdx.x;
    int b = bc >> 8;              // / C_
    int c = bc & (C_ - 1);
    int tid = threadIdx.x;
    const f4* frow = reinterpret_cast<const f4*>(fea + ((size_t)b * C_ + c) * HW_);
    const unsigned int* prow = predp + (size_t)b * WPS_;

    float acc[K_] = {};
    #pragma unroll 4
    for (int i = tid; i < WPS_; i += 256) {
        f4 v = __builtin_nontemporal_load(frow + i);
        unsigned u = prow[i];
        int k0 = u & 255, k1 = (u >> 8) & 255, k2 = (u >> 16) & 255, k3 = u >> 24;
        #pragma unroll
        for (int k = 0; k < K_; ++k) {
            acc[k] += (k0 == k ? v.x : 0.f)
                    + (k1 == k ? v.y : 0.f)
                    + (k2 == k ? v.z : 0.f)
                    + (k3 == k ? v.w : 0.f);
        }
    }

    __shared__ float red[4][K_];
    int lane = tid & 63, wv = tid >> 6;
    #pragma unroll
    for (int k = 0; k < K_; ++k) {
        float v = acc[k];
        #pragma unroll
        for (int off = 32; off > 0; off >>= 1) v += __shfl_down(v, off);
        if (lane == 0) red[wv][k] = v;
    }
    __syncthreads();
    if (tid < K_)
        sums[((size_t)b * K_ + tid) * C_ + c] =
            red[0][tid] + red[1][tid] + red[2][tid] + red[3][tid];
}

// ---------------------------------------------------------------------------
// Kernel 3: contrastive tail, one block per (b,k); last block folds in the
// valid/denom masking + final reductions. Dot products use 16 independent
// accumulators (16 loads in flight) to hide L2 latency — the round-4 serial
// `acc +=` chain was the latency bottleneck (R6 post-mortem).
// ---------------------------------------------------------------------------
__global__ __launch_bounds__(256) void loss_kernel(
    const float* __restrict__ sums, const int* __restrict__ counts_blk,
    const float* __restrict__ queues, float* __restrict__ logprob,
    int* __restrict__ counts_g, int* __restrict__ flag, float* __restrict__ out)
{
    int bk = blockIdx.x;
    int b = bk / K_;
    int k = bk - b * K_;
    int tid = threadIdx.x, lane = tid & 63, wv = tid >> 6;

    __shared__ float key[C_];
    __shared__ float wred[4];
    __shared__ float sumE_s[K_];
    __shared__ float lpos_s[Q_];
    __shared__ int   cnt_s[K_];
    __shared__ int   last_s;

    // per-sample class counts: sum the 16 per-block vectors
    if (tid < K_) {
        int s = 0;
        #pragma unroll
        for (int blk = 0; blk < PB_; ++blk)
            s += counts_blk[(b * PB_ + blk) * K_ + tid];
        cnt_s[tid] = s;
        if (k == 0) counts_g[b * K_ + tid] = s;   // for the final reduction
    }
    __syncthreads();

    // prev (faithful cummax off-by-one): last present class with index < k
    int prev = -1;
    #pragma unroll
    for (int j = 0; j < K_; ++j)
        if (j < k && cnt_s[j] > 0) prev = j;
    int pk = prev < 0 ? 0 : prev;   // query = keys[max(prev,0)]

    // mean of class pk, L2-normalized over C (thread tid owns channel tid)
    float m = sums[((size_t)b * K_ + pk) * C_ + tid] / fmaxf((float)cnt_s[pk], 1.0f);
    float s = m * m;
    #pragma unroll
    for (int off = 32; off > 0; off >>= 1) s += __shfl_down(s, off);
    if (lane == 0) wred[wv] = s;
    __syncthreads();
    float nrm = sqrtf(wred[0] + wred[1] + wred[2] + wred[3]);
    key[tid] = m / fmaxf(nrm, 1e-12f);
    __syncthreads();

    // sim[k,j,:]: waves own j's, lanes = q. 16 partial accumulators -> 16
    // independent L2 loads in flight per wave (latency hiding via ILP; this
    // kernel runs at ~1 wave/SIMD so TLP can't help).
    for (int j = wv; j < K_; j += 4) {
        const float* qj = queues + (size_t)j * C_ * Q_ + lane;
        float pa[16];
        #pragma unroll
        for (int u = 0; u < 16; ++u) pa[u] = 0.f;
        for (int cc = 0; cc < C_; cc += 16) {
            #pragma unroll
            for (int u = 0; u < 16; ++u)
                pa[u] += key[cc + u] * qj[(size_t)(cc + u) * Q_];
        }
        float acc = (((pa[0] + pa[1]) + (pa[2] + pa[3])) +
                     ((pa[4] + pa[5]) + (pa[6] + pa[7]))) +
                    (((pa[8] + pa[9]) + (pa[10] + pa[11])) +
                     ((pa[12] + pa[13]) + (pa[14] + pa[15])));
        acc = acc / T_;
        float e = expf(acc);
        float se = e;
        #pragma unroll
        for (int off = 32; off > 0; off >>= 1) se += __shfl_down(se, off);
        if (lane == 0) sumE_s[j] = se;
        if (j == k) lpos_s[lane] = acc;
    }
    __syncthreads();

    if (wv == 0) {
        float neg = 0.f;
        #pragma unroll
        for (int j = 0; j < K_; ++j)
            if (j != k) neg += sumE_s[j];
        float lp = lpos_s[lane];
        float term = lp - logf(expf(lp) + neg);
        #pragma unroll
        for (int off = 32; off > 0; off >>= 1) term += __shfl_down(term, off);
        if (lane == 0) logprob[bk] = term * (1.0f / (float)Q_);
    }
    __syncthreads();

    // last-block final reduction
    if (tid == 0) {
        __threadfence();
        last_s = (atomicAdd(flag, 1) == B_ * K_ - 1);
    }
    __syncthreads();
    if (last_s && wv == 0) {
        __threadfence();
        float per = 0.f;
        if (lane < B_) {
            int last = -1, smallest = -1, npres = 0;
            float lsum = 0.f;
            #pragma unroll
            for (int kk = 0; kk < K_; ++kk) {
                bool pres = counts_g[lane * K_ + kk] > 0;
                bool valid = pres && smallest >= 0 && last >= 0;
                if (valid) lsum += -logprob[lane * K_ + kk];
                if (pres && smallest < 0) smallest = kk;
                if (pres) { ++npres; last = kk; }
            }
            int denom = npres - 1;
            per = (denom > 0) ? (lsum / (float)denom) : 0.f;
        }
        #pragma unroll
        for (int off = 32; off > 0; off >>= 1) per += __shfl_down(per, off);
        if (lane == 0) out[0] = per / (float)B_;
    }
}

// ---------------------------------------------------------------------------
extern "C" void kernel_launch(void* const* d_in, const int* in_sizes, int n_in,
                              void* d_out, int out_size, void* d_ws, size_t ws_size,
                              hipStream_t stream)
{
    const float* res1     = (const float*)d_in[0];
    const float* fea1     = (const float*)d_in[1];
    const float* queues   = (const float*)d_in[2];
    const int*   gt       = (const int*)d_in[3];
    const int*   label_bs = (const int*)d_in[4];
    float* out = (float*)d_out;

    char* ws = (char*)d_ws;
    unsigned int* predp = (unsigned int*)ws;                        // 256 KB
    float* sums       = (float*)(ws + (size_t)B_ * WPS_ * 4);       // B*K*C floats
    int*   counts_blk = (int*)(sums + (size_t)B_ * K_ * C_);        // 256*K ints
    int*   counts_g   = counts_blk + B_ * PB_ * K_;                 // B*K ints
    int*   flag       = counts_g + B_ * K_;                         // 1 int
    float* logprob    = (float*)(flag + 1);                         // B*K floats

    pred_kernel<<<B_ * WPS_ / 256, 256, 0, stream>>>(res1, gt, label_bs, predp,
                                                     counts_blk, flag);
    segsum_kernel<<<B_ * C_, 256, 0, stream>>>(fea1, predp, sums);
    loss_kernel<<<B_ * K_, 256, 0, stream>>>(sums, counts_blk, queues, logprob,
                                             counts_g, flag, out);
}

// Round 8
// 61.854 us; speedup vs baseline: 5.2412x; 1.6623x over previous
//
#include <hip/hip_runtime.h>
#include <cstddef>

constexpr int B_  = 16;
constexpr int K_  = 5;
constexpr int C_  = 256;
constexpr int HW_ = 128 * 128;
constexpr int Q_  = 64;
constexpr float T_ = 0.2f;
constexpr int WPS_ = HW_ / 4;   // packed words per sample = 4096
constexpr int PB_  = 16;        // pred blocks per sample (4096/256)

typedef float f4 __attribute__((ext_vector_type(4)));

// ---------------------------------------------------------------------------
// Kernel 1: per-pixel prediction (byte-packed, 4 px/uint) + per-block counts.
// (byte-identical to round 4 — known good)
// ---------------------------------------------------------------------------
__global__ __launch_bounds__(256) void pred_kernel(
    const float* __restrict__ res1, const int* __restrict__ gt,
    const int* __restrict__ label_bs, unsigned int* __restrict__ predp,
    int* __restrict__ counts_blk, int* __restrict__ flag)
{
    if (blockIdx.x == 0 && threadIdx.x == 0) *flag = 0;

    int idx = blockIdx.x * 256 + threadIdx.x;   // word index, 0 .. B*HW/4-1
    int b  = idx >> 12;                         // 4096 words per sample
    int p4 = idx & 4095;
    int lb = label_bs[0];
    int k0, k1, k2, k3;
    if (b < lb) {
        int4 g = reinterpret_cast<const int4*>(gt + (size_t)b * HW_)[p4];
        k0 = g.x; k1 = g.y; k2 = g.z; k3 = g.w;
    } else {
        const f4* r = reinterpret_cast<const f4*>(res1 + (size_t)b * K_ * HW_) + p4;
        f4 best = __builtin_nontemporal_load(r);
        k0 = k1 = k2 = k3 = 0;
        #pragma unroll
        for (int k = 1; k < K_; ++k) {
            f4 v = __builtin_nontemporal_load(r + (size_t)k * WPS_);
            if (v.x > best.x) { best.x = v.x; k0 = k; }   // strict >: first max
            if (v.y > best.y) { best.y = v.y; k1 = k; }
            if (v.z > best.z) { best.z = v.z; k2 = k; }
            if (v.w > best.w) { best.w = v.w; k3 = k; }
        }
    }
    predp[idx] = (unsigned)(k0 & 0xFF) | ((unsigned)(k1 & 0xFF) << 8)
               | ((unsigned)(k2 & 0xFF) << 16) | ((unsigned)(k3 & 0xFF) << 24);

    int cnt[K_];
    #pragma unroll
    for (int k = 0; k < K_; ++k)
        cnt[k] = (k0 == k) + (k1 == k) + (k2 == k) + (k3 == k);

    int lane = threadIdx.x & 63, wv = threadIdx.x >> 6;
    __shared__ int redc[4][K_];
    #pragma unroll
    for (int k = 0; k < K_; ++k) {
        int v = cnt[k];
        #pragma unroll
        for (int off = 32; off > 0; off >>= 1) v += __shfl_down(v, off);
        if (lane == 0) redc[wv][k] = v;
    }
    __syncthreads();
    if (threadIdx.x < K_)
        counts_blk[blockIdx.x * K_ + threadIdx.x] =
            redc[0][threadIdx.x] + redc[1][threadIdx.x] +
            redc[2][threadIdx.x] + redc[3][threadIdx.x];
}

// ---------------------------------------------------------------------------
// Kernel 2: masked segment sums. One block per (b,c) row (4096 blocks);
// NT float4 streaming + byte-packed preds; unique-owner direct writes.
// (byte-identical to round 4 — known good)
// ---------------------------------------------------------------------------
__global__ __launch_bounds__(256) void segsum_kernel(
    const float* __restrict__ fea, const unsigned int* __restrict__ predp,
    float* __restrict__ sums)
{
    int bc = blockIdx.x;
    int b = bc >> 8;              // / C_
    int c = bc & (C_ - 1);
    int tid = threadIdx.x;
    const f4* frow = reinterpret_cast<const f4*>(fea + ((size_t)b * C_ + c) * HW_);
    const unsigned int* prow = predp + (size_t)b * WPS_;

    float acc[K_] = {};
    #pragma unroll 4
    for (int i = tid; i < WPS_; i += 256) {
        f4 v = __builtin_nontemporal_load(frow + i);
        unsigned u = prow[i];
        int k0 = u & 255, k1 = (u >> 8) & 255, k2 = (u >> 16) & 255, k3 = u >> 24;
        #pragma unroll
        for (int k = 0; k < K_; ++k) {
            acc[k] += (k0 == k ? v.x : 0.f)
                    + (k1 == k ? v.y : 0.f)
                    + (k2 == k ? v.z : 0.f)
                    + (k3 == k ? v.w : 0.f);
        }
    }

    __shared__ float red[4][K_];
    int lane = tid & 63, wv = tid >> 6;
    #pragma unroll
    for (int k = 0; k < K_; ++k) {
        float v = acc[k];
        #pragma unroll
        for (int off = 32; off > 0; off >>= 1) v += __shfl_down(v, off);
        if (lane == 0) red[wv][k] = v;
    }
    __syncthreads();
    if (tid < K_)
        sums[((size_t)b * K_ + tid) * C_ + c] =
            red[0][tid] + red[1][tid] + red[2][tid] + red[3][tid];
}

// ---------------------------------------------------------------------------
// Kernel 3: contrastive tail, one block per (b,k), 320 threads = 5 waves:
// wave j computes the single j-dot (round-4's serial-chain form, which the
// compiler pipelines well — R7 showed hand-batched accumulators destroy MLP).
// Last block folds in the valid/denom masking + final reductions.
// ---------------------------------------------------------------------------
__global__ __launch_bounds__(320) void loss_kernel(
    const float* __restrict__ sums, const int* __restrict__ counts_blk,
    const float* __restrict__ queues, float* __restrict__ logprob,
    int* __restrict__ counts_g, int* __restrict__ flag, float* __restrict__ out)
{
    int bk = blockIdx.x;
    int b = bk / K_;
    int k = bk - b * K_;
    int tid = threadIdx.x, lane = tid & 63, wv = tid >> 6;   // wv in 0..4

    __shared__ float key[C_];
    __shared__ float wred[5];
    __shared__ float sumE_s[K_];
    __shared__ float lpos_s[Q_];
    __shared__ int   cnt_s[K_];
    __shared__ int   last_s;

    // per-sample class counts: sum the 16 per-block vectors
    if (tid < K_) {
        int s = 0;
        #pragma unroll
        for (int blk = 0; blk < PB_; ++blk)
            s += counts_blk[(b * PB_ + blk) * K_ + tid];
        cnt_s[tid] = s;
        if (k == 0) counts_g[b * K_ + tid] = s;   // for the final reduction
    }
    __syncthreads();

    // prev (faithful cummax off-by-one): last present class with index < k
    int prev = -1;
    #pragma unroll
    for (int j = 0; j < K_; ++j)
        if (j < k && cnt_s[j] > 0) prev = j;
    int pk = prev < 0 ? 0 : prev;   // query = keys[max(prev,0)]

    // mean of class pk, L2-normalized over C (threads 0..255 own channels;
    // wave 4 contributes zero to the norm)
    float m = (tid < C_)
        ? sums[((size_t)b * K_ + pk) * C_ + tid] / fmaxf((float)cnt_s[pk], 1.0f)
        : 0.f;
    float s = m * m;
    #pragma unroll
    for (int off = 32; off > 0; off >>= 1) s += __shfl_down(s, off);
    if (lane == 0) wred[wv] = s;
    __syncthreads();
    float nrm = sqrtf(wred[0] + wred[1] + wred[2] + wred[3] + wred[4]);
    if (tid < C_) key[tid] = m / fmaxf(nrm, 1e-12f);
    __syncthreads();

    // sim[k,j,:]: wave wv owns exactly j = wv; lanes = q. Serial-chain dot
    // (compiler software-pipelines the independent loads).
    {
        int j = wv;   // 0..4 == K_ waves, one dot each
        const float* qj = queues + (size_t)j * C_ * Q_ + lane;
        float acc = 0.f;
        for (int c = 0; c < C_; ++c)
            acc += key[c] * qj[(size_t)c * Q_];
        acc = acc / T_;
        float e = expf(acc);
        float se = e;
        #pragma unroll
        for (int off = 32; off > 0; off >>= 1) se += __shfl_down(se, off);
        if (lane == 0) sumE_s[j] = se;
        if (j == k) lpos_s[lane] = acc;
    }
    __syncthreads();

    if (wv == 0) {
        float neg = 0.f;
        #pragma unroll
        for (int j = 0; j < K_; ++j)
            if (j != k) neg += sumE_s[j];
        float lp = lpos_s[lane];
        float term = lp - logf(expf(lp) + neg);
        #pragma unroll
        for (int off = 32; off > 0; off >>= 1) term += __shfl_down(term, off);
        if (lane == 0) logprob[bk] = term * (1.0f / (float)Q_);
    }
    __syncthreads();

    // last-block final reduction
    if (tid == 0) {
        __threadfence();
        last_s = (atomicAdd(flag, 1) == B_ * K_ - 1);
    }
    __syncthreads();
    if (last_s && wv == 0) {
        __threadfence();
        float per = 0.f;
        if (lane < B_) {
            int last = -1, smallest = -1, npres = 0;
            float lsum = 0.f;
            #pragma unroll
            for (int kk = 0; kk < K_; ++kk) {
                bool pres = counts_g[lane * K_ + kk] > 0;
                bool valid = pres && smallest >= 0 && last >= 0;
                if (valid) lsum += -logprob[lane * K_ + kk];
                if (pres && smallest < 0) smallest = kk;
                if (pres) { ++npres; last = kk; }
            }
            int denom = npres - 1;
            per = (denom > 0) ? (lsum / (float)denom) : 0.f;
        }
        #pragma unroll
        for (int off = 32; off > 0; off >>= 1) per += __shfl_down(per, off);
        if (lane == 0) out[0] = per / (float)B_;
    }
}

// ---------------------------------------------------------------------------
extern "C" void kernel_launch(void* const* d_in, const int* in_sizes, int n_in,
                              void* d_out, int out_size, void* d_ws, size_t ws_size,
                              hipStream_t stream)
{
    const float* res1     = (const float*)d_in[0];
    const float* fea1     = (const float*)d_in[1];
    const float* queues   = (const float*)d_in[2];
    const int*   gt       = (const int*)d_in[3];
    const int*   label_bs = (const int*)d_in[4];
    float* out = (float*)d_out;

    char* ws = (char*)d_ws;
    unsigned int* predp = (unsigned int*)ws;                        // 256 KB
    float* sums       = (float*)(ws + (size_t)B_ * WPS_ * 4);       // B*K*C floats
    int*   counts_blk = (int*)(sums + (size_t)B_ * K_ * C_);        // 256*K ints
    int*   counts_g   = counts_blk + B_ * PB_ * K_;                 // B*K ints
    int*   flag       = counts_g + B_ * K_;                         // 1 int
    float* logprob    = (float*)(flag + 1);                         // B*K floats

    pred_kernel<<<B_ * WPS_ / 256, 256, 0, stream>>>(res1, gt, label_bs, predp,
                                                     counts_blk, flag);
    segsum_kernel<<<B_ * C_, 256, 0, stream>>>(fea1, predp, sums);
    loss_kernel<<<B_ * K_, 320, 0, stream>>>(sums, counts_blk, queues, logprob,
                                             counts_g, flag, out);
}